// Round 1
// baseline (1494.785 us; speedup 1.0000x reference)
//
#include <hip/hip_runtime.h>
#include <hip/hip_bf16.h>

// JetGNN: 2-layer SAGEConv(mean) + ReLU + global_mean_pool + Linear(64->2)
// Strategy: build CSR-by-dst once per call (deg -> scan -> fill), then
// node-parallel mean aggregation (no float atomics), LDS-staged dense
// transforms, layer-2 dense fused with pooling atomics.

#define WS_ALIGN 64

// ---------- CSR construction ----------

__global__ void deg_kernel(const int* __restrict__ dst, int* __restrict__ deg, int E) {
    int e = blockIdx.x * blockDim.x + threadIdx.x;
    if (e < E) atomicAdd(&deg[dst[e]], 1);
}

__global__ void cnt_kernel(const int* __restrict__ batch, int* __restrict__ cnt, int N) {
    int i = blockIdx.x * blockDim.x + threadIdx.x;
    if (i < N) atomicAdd(&cnt[batch[i]], 1);
}

// single-block exclusive scan of deg[N] -> offsets[N+1]; cursor[i] = offsets[i]
__global__ void scan_kernel(const int* __restrict__ deg, int* __restrict__ offsets,
                            int* __restrict__ cursor, int N) {
    __shared__ int partial[1024];
    const int t = threadIdx.x;
    const int chunk = (N + 1023) / 1024;
    const int beg = t * chunk;
    const int end = min(beg + chunk, N);
    int s = 0;
    for (int i = beg; i < end; ++i) s += deg[i];
    partial[t] = s;
    __syncthreads();
    // Hillis-Steele inclusive scan over 1024 partials
    for (int off = 1; off < 1024; off <<= 1) {
        int v = (t >= off) ? partial[t - off] : 0;
        __syncthreads();
        partial[t] += v;
        __syncthreads();
    }
    int run = (t > 0) ? partial[t - 1] : 0;
    for (int i = beg; i < end; ++i) {
        offsets[i] = run;
        cursor[i]  = run;
        run += deg[i];
    }
    if (t == 1023) offsets[N] = partial[1023];
}

__global__ void fill_kernel(const int* __restrict__ src, const int* __restrict__ dst,
                            int* __restrict__ cursor, int* __restrict__ csr_src, int E) {
    int e = blockIdx.x * blockDim.x + threadIdx.x;
    if (e < E) {
        int d = dst[e];
        int p = atomicAdd(&cursor[d], 1);
        csr_src[p] = src[e];
    }
}

// ---------- mean aggregation (node-parallel, D/4 threads per node) ----------

template <int D>
__global__ void agg_kernel(const float* __restrict__ feat,
                           const int* __restrict__ csr_src,
                           const int* __restrict__ offsets,
                           float* __restrict__ agg, int N) {
    constexpr int TPN = D / 4;                 // threads per node (float4 chunks)
    int tid  = blockIdx.x * blockDim.x + threadIdx.x;
    int node = tid / TPN;
    int part = tid % TPN;
    if (node >= N) return;
    const int beg = offsets[node];
    const int end = offsets[node + 1];
    float4 acc = make_float4(0.f, 0.f, 0.f, 0.f);
    for (int k = beg; k < end; ++k) {
        int s = csr_src[k];
        const float4 v = *reinterpret_cast<const float4*>(feat + (size_t)s * D + part * 4);
        acc.x += v.x; acc.y += v.y; acc.z += v.z; acc.w += v.w;
    }
    const float inv = 1.0f / fmaxf((float)(end - beg), 1.0f);
    acc.x *= inv; acc.y *= inv; acc.z *= inv; acc.w *= inv;
    *reinterpret_cast<float4*>(agg + (size_t)node * D + part * 4) = acc;
}

// ---------- dense: out[i][o] = relu(agg[i]·Wl[o] + x[i]·Wr[o] + b[o]) ----------
// block = 256 = 4 nodes x 64 outputs. Weights staged in LDS with +1 pad
// (stride DIN+1 -> (o + c) % 32 distinct per lane: conflict-free).

template <int DIN, bool POOL>
__launch_bounds__(256)
__global__ void dense_kernel(const float* __restrict__ agg,
                             const float* __restrict__ xin,
                             const float* __restrict__ Wl,
                             const float* __restrict__ Wr,
                             const float* __restrict__ bias,
                             float* __restrict__ hout,
                             const int* __restrict__ batch,
                             float* __restrict__ pool_sum,
                             int N) {
    constexpr int PAD = DIN + 1;
    __shared__ float Wl_s[64 * PAD];
    __shared__ float Wr_s[64 * PAD];
    __shared__ float a_s[4 * DIN];
    __shared__ float x_s[4 * DIN];
    const int tid = threadIdx.x;
    for (int i = tid; i < 64 * DIN; i += 256) {
        int r = i / DIN, c = i % DIN;
        Wl_s[r * PAD + c] = Wl[i];
        Wr_s[r * PAD + c] = Wr[i];
    }
    const int ln   = tid >> 6;      // local node 0..3
    const int o    = tid & 63;      // output channel
    const int node = blockIdx.x * 4 + ln;
    if (o < DIN && node < N) {
        a_s[ln * DIN + o] = agg[(size_t)node * DIN + o];
        x_s[ln * DIN + o] = xin[(size_t)node * DIN + o];
    }
    __syncthreads();
    if (node >= N) return;
    float acc = bias[o];
#pragma unroll
    for (int c = 0; c < DIN; ++c) {
        acc = fmaf(a_s[ln * DIN + c], Wl_s[o * PAD + c], acc);
        acc = fmaf(x_s[ln * DIN + c], Wr_s[o * PAD + c], acc);
    }
    acc = fmaxf(acc, 0.0f);
    if (POOL) {
        atomicAdd(&pool_sum[(size_t)batch[node] * 64 + o], acc);
    } else {
        hout[(size_t)node * 64 + o] = acc;
    }
}

// ---------- head: out[g][o] = b_lin[o] + (pool_sum[g]/cnt[g])·W_lin[o] ----------

__global__ void final_kernel(const float* __restrict__ pool_sum,
                             const int* __restrict__ cnt,
                             const float* __restrict__ W_lin,
                             const float* __restrict__ b_lin,
                             float* __restrict__ out, int G) {
    int t = blockIdx.x * blockDim.x + threadIdx.x;
    if (t >= G * 2) return;
    int g = t >> 1, o = t & 1;
    float inv = 1.0f / fmaxf((float)cnt[g], 1.0f);
    float acc = b_lin[o];
#pragma unroll
    for (int c = 0; c < 64; ++c)
        acc = fmaf(pool_sum[(size_t)g * 64 + c] * inv, W_lin[o * 64 + c], acc);
    out[t] = acc;
}

extern "C" void kernel_launch(void* const* d_in, const int* in_sizes, int n_in,
                              void* d_out, int out_size, void* d_ws, size_t ws_size,
                              hipStream_t stream) {
    const float* x     = (const float*)d_in[0];
    const int*   ei    = (const int*)d_in[1];
    const int*   batch = (const int*)d_in[2];
    const float* W1_l  = (const float*)d_in[3];
    const float* b1    = (const float*)d_in[4];
    const float* W1_r  = (const float*)d_in[5];
    const float* W2_l  = (const float*)d_in[6];
    const float* b2    = (const float*)d_in[7];
    const float* W2_r  = (const float*)d_in[8];
    const float* W_lin = (const float*)d_in[9];
    const float* b_lin = (const float*)d_in[10];

    const int N = in_sizes[0] / 32;
    const int E = in_sizes[1] / 2;
    const int G = out_size / 2;
    const int* src = ei;
    const int* dst = ei + E;

    // workspace carve (64B-aligned regions)
    char* p = (char*)d_ws;
    auto carve = [&](size_t bytes) -> void* {
        void* r = (void*)p;
        p += (bytes + (WS_ALIGN - 1)) / WS_ALIGN * WS_ALIGN;
        return r;
    };
    int*   deg     = (int*)carve((size_t)N * 4);
    int*   offsets = (int*)carve((size_t)(N + 1) * 4);
    int*   cursor  = (int*)carve((size_t)N * 4);
    int*   csr_src = (int*)carve((size_t)E * 4);
    float* agg     = (float*)carve((size_t)N * 64 * 4);
    float* h1      = (float*)carve((size_t)N * 64 * 4);
    float* pool    = (float*)carve((size_t)G * 64 * 4);
    int*   cnt     = (int*)carve((size_t)G * 4);
    float* out     = (float*)d_out;

    hipMemsetAsync(deg, 0, (size_t)N * 4, stream);
    hipMemsetAsync(pool, 0, (size_t)G * 64 * 4, stream);
    hipMemsetAsync(cnt, 0, (size_t)G * 4, stream);

    const int TB = 256;
    deg_kernel<<<(E + TB - 1) / TB, TB, 0, stream>>>(dst, deg, E);
    cnt_kernel<<<(N + TB - 1) / TB, TB, 0, stream>>>(batch, cnt, N);
    scan_kernel<<<1, 1024, 0, stream>>>(deg, offsets, cursor, N);
    fill_kernel<<<(E + TB - 1) / TB, TB, 0, stream>>>(src, dst, cursor, csr_src, E);

    // layer 1: aggregate x (D=32), dense 32->64 + relu -> h1
    agg_kernel<32><<<((size_t)N * 8 + TB - 1) / TB, TB, 0, stream>>>(x, csr_src, offsets, agg, N);
    dense_kernel<32, false><<<(N + 3) / 4, TB, 0, stream>>>(agg, x, W1_l, W1_r, b1, h1,
                                                            nullptr, nullptr, N);

    // layer 2: aggregate h1 (D=64), dense 64->64 + relu fused with pooling
    agg_kernel<64><<<((size_t)N * 16 + TB - 1) / TB, TB, 0, stream>>>(h1, csr_src, offsets, agg, N);
    dense_kernel<64, true><<<(N + 3) / 4, TB, 0, stream>>>(agg, h1, W2_l, W2_r, b2, nullptr,
                                                           batch, pool, N);

    final_kernel<<<(G * 2 + TB - 1) / TB, TB, 0, stream>>>(pool, cnt, W_lin, b_lin, out, G);
}

// Round 2
// 1048.731 us; speedup vs baseline: 1.4253x; 1.4253x over previous
//
#include <hip/hip_runtime.h>
#include <hip/hip_bf16.h>

// JetGNN: 2-layer SAGEConv(mean) + ReLU + global_mean_pool + Linear(64->2)
// R1: replaced single-block scan (454us, 0.15% occupancy) with 3-phase
// hierarchical scan (coalesced, ~30us total).

#define WS_ALIGN 64
#define SCAN_CHUNK 1024   // elements per block in hierarchical scan (256 thr x 4)

// ---------- CSR construction ----------

__global__ void deg_kernel(const int* __restrict__ dst, int* __restrict__ deg, int E) {
    int e = blockIdx.x * blockDim.x + threadIdx.x;
    if (e < E) atomicAdd(&deg[dst[e]], 1);
}

__global__ void cnt_kernel(const int* __restrict__ batch, int* __restrict__ cnt, int N) {
    int i = blockIdx.x * blockDim.x + threadIdx.x;
    if (i < N) atomicAdd(&cnt[batch[i]], 1);
}

// ---- hierarchical exclusive scan of deg[N] -> offsets[N+1], cursor[N] ----
// phase 1: per-thread sum of 4 consecutive elems; LDS scan over 256 thread
// sums; store per-thread exclusive prefix and per-block total.
__global__ void scan1_kernel(const int* __restrict__ deg,
                             int* __restrict__ threadPrefix,
                             int* __restrict__ blockSums, int N) {
    __shared__ int s[256];
    const int t = threadIdx.x;
    const int base = blockIdx.x * SCAN_CHUNK + t * 4;
    int sum = 0;
#pragma unroll
    for (int j = 0; j < 4; ++j) {
        int i = base + j;
        if (i < N) sum += deg[i];
    }
    s[t] = sum;
    __syncthreads();
    // Hillis-Steele inclusive scan over 256
#pragma unroll
    for (int off = 1; off < 256; off <<= 1) {
        int v = (t >= off) ? s[t - off] : 0;
        __syncthreads();
        s[t] += v;
        __syncthreads();
    }
    threadPrefix[blockIdx.x * 256 + t] = s[t] - sum;   // exclusive
    if (t == 255) blockSums[blockIdx.x] = s[255];
}

// phase 2: single block scans blockSums[nb] (nb <= 1024) -> exclusive
__global__ void scan2_kernel(int* __restrict__ blockSums, int nb) {
    __shared__ int s[1024];
    const int t = threadIdx.x;
    int v = (t < nb) ? blockSums[t] : 0;
    s[t] = v;
    __syncthreads();
    for (int off = 1; off < 1024; off <<= 1) {
        int u = (t >= off) ? s[t - off] : 0;
        __syncthreads();
        s[t] += u;
        __syncthreads();
    }
    if (t < nb) blockSums[t] = s[t] - v;               // exclusive
}

// phase 3: replay 4 elems with global base; write offsets + cursor
__global__ void scan3_kernel(const int* __restrict__ deg,
                             const int* __restrict__ threadPrefix,
                             const int* __restrict__ blockSums,
                             int* __restrict__ offsets,
                             int* __restrict__ cursor, int N, int E) {
    const int t = threadIdx.x;
    const int base = blockIdx.x * SCAN_CHUNK + t * 4;
    int run = blockSums[blockIdx.x] + threadPrefix[blockIdx.x * 256 + t];
#pragma unroll
    for (int j = 0; j < 4; ++j) {
        int i = base + j;
        if (i < N) {
            offsets[i] = run;
            cursor[i]  = run;
            run += deg[i];
        }
    }
    if (blockIdx.x == 0 && t == 0) offsets[N] = E;
}

__global__ void fill_kernel(const int* __restrict__ src, const int* __restrict__ dst,
                            int* __restrict__ cursor, int* __restrict__ csr_src, int E) {
    int e = blockIdx.x * blockDim.x + threadIdx.x;
    if (e < E) {
        int d = dst[e];
        int p = atomicAdd(&cursor[d], 1);
        csr_src[p] = src[e];
    }
}

// ---------- mean aggregation (node-parallel, D/4 threads per node) ----------

template <int D>
__global__ void agg_kernel(const float* __restrict__ feat,
                           const int* __restrict__ csr_src,
                           const int* __restrict__ offsets,
                           float* __restrict__ agg, int N) {
    constexpr int TPN = D / 4;                 // threads per node (float4 chunks)
    int tid  = blockIdx.x * blockDim.x + threadIdx.x;
    int node = tid / TPN;
    int part = tid % TPN;
    if (node >= N) return;
    const int beg = offsets[node];
    const int end = offsets[node + 1];
    float4 acc = make_float4(0.f, 0.f, 0.f, 0.f);
    for (int k = beg; k < end; ++k) {
        int s = csr_src[k];
        const float4 v = *reinterpret_cast<const float4*>(feat + (size_t)s * D + part * 4);
        acc.x += v.x; acc.y += v.y; acc.z += v.z; acc.w += v.w;
    }
    const float inv = 1.0f / fmaxf((float)(end - beg), 1.0f);
    acc.x *= inv; acc.y *= inv; acc.z *= inv; acc.w *= inv;
    *reinterpret_cast<float4*>(agg + (size_t)node * D + part * 4) = acc;
}

// ---------- dense: out[i][o] = relu(agg[i]·Wl[o] + x[i]·Wr[o] + b[o]) ----------

template <int DIN, bool POOL>
__launch_bounds__(256)
__global__ void dense_kernel(const float* __restrict__ agg,
                             const float* __restrict__ xin,
                             const float* __restrict__ Wl,
                             const float* __restrict__ Wr,
                             const float* __restrict__ bias,
                             float* __restrict__ hout,
                             const int* __restrict__ batch,
                             float* __restrict__ pool_sum,
                             int N) {
    constexpr int PAD = DIN + 1;
    __shared__ float Wl_s[64 * PAD];
    __shared__ float Wr_s[64 * PAD];
    __shared__ float a_s[4 * DIN];
    __shared__ float x_s[4 * DIN];
    const int tid = threadIdx.x;
    for (int i = tid; i < 64 * DIN; i += 256) {
        int r = i / DIN, c = i % DIN;
        Wl_s[r * PAD + c] = Wl[i];
        Wr_s[r * PAD + c] = Wr[i];
    }
    const int ln   = tid >> 6;      // local node 0..3
    const int o    = tid & 63;      // output channel
    const int node = blockIdx.x * 4 + ln;
    if (o < DIN && node < N) {
        a_s[ln * DIN + o] = agg[(size_t)node * DIN + o];
        x_s[ln * DIN + o] = xin[(size_t)node * DIN + o];
    }
    __syncthreads();
    if (node >= N) return;
    float acc = bias[o];
#pragma unroll
    for (int c = 0; c < DIN; ++c) {
        acc = fmaf(a_s[ln * DIN + c], Wl_s[o * PAD + c], acc);
        acc = fmaf(x_s[ln * DIN + c], Wr_s[o * PAD + c], acc);
    }
    acc = fmaxf(acc, 0.0f);
    if (POOL) {
        atomicAdd(&pool_sum[(size_t)batch[node] * 64 + o], acc);
    } else {
        hout[(size_t)node * 64 + o] = acc;
    }
}

// ---------- head ----------

__global__ void final_kernel(const float* __restrict__ pool_sum,
                             const int* __restrict__ cnt,
                             const float* __restrict__ W_lin,
                             const float* __restrict__ b_lin,
                             float* __restrict__ out, int G) {
    int t = blockIdx.x * blockDim.x + threadIdx.x;
    if (t >= G * 2) return;
    int g = t >> 1, o = t & 1;
    float inv = 1.0f / fmaxf((float)cnt[g], 1.0f);
    float acc = b_lin[o];
#pragma unroll
    for (int c = 0; c < 64; ++c)
        acc = fmaf(pool_sum[(size_t)g * 64 + c] * inv, W_lin[o * 64 + c], acc);
    out[t] = acc;
}

extern "C" void kernel_launch(void* const* d_in, const int* in_sizes, int n_in,
                              void* d_out, int out_size, void* d_ws, size_t ws_size,
                              hipStream_t stream) {
    const float* x     = (const float*)d_in[0];
    const int*   ei    = (const int*)d_in[1];
    const int*   batch = (const int*)d_in[2];
    const float* W1_l  = (const float*)d_in[3];
    const float* b1    = (const float*)d_in[4];
    const float* W1_r  = (const float*)d_in[5];
    const float* W2_l  = (const float*)d_in[6];
    const float* b2    = (const float*)d_in[7];
    const float* W2_r  = (const float*)d_in[8];
    const float* W_lin = (const float*)d_in[9];
    const float* b_lin = (const float*)d_in[10];

    const int N = in_sizes[0] / 32;
    const int E = in_sizes[1] / 2;
    const int G = out_size / 2;
    const int* src = ei;
    const int* dst = ei + E;

    char* p = (char*)d_ws;
    auto carve = [&](size_t bytes) -> void* {
        void* r = (void*)p;
        p += (bytes + (WS_ALIGN - 1)) / WS_ALIGN * WS_ALIGN;
        return r;
    };
    const int nScanBlocks = (N + SCAN_CHUNK - 1) / SCAN_CHUNK;   // 196 for N=200000
    int*   deg     = (int*)carve((size_t)N * 4);
    int*   offsets = (int*)carve((size_t)(N + 1) * 4);
    int*   cursor  = (int*)carve((size_t)N * 4);
    int*   csr_src = (int*)carve((size_t)E * 4);
    float* agg     = (float*)carve((size_t)N * 64 * 4);
    float* h1      = (float*)carve((size_t)N * 64 * 4);
    float* pool    = (float*)carve((size_t)G * 64 * 4);
    int*   cnt     = (int*)carve((size_t)G * 4);
    int*   thrPfx  = (int*)carve((size_t)nScanBlocks * 256 * 4);
    int*   blkSums = (int*)carve((size_t)nScanBlocks * 4);
    float* out     = (float*)d_out;

    hipMemsetAsync(deg, 0, (size_t)N * 4, stream);
    hipMemsetAsync(pool, 0, (size_t)G * 64 * 4, stream);
    hipMemsetAsync(cnt, 0, (size_t)G * 4, stream);

    const int TB = 256;
    deg_kernel<<<(E + TB - 1) / TB, TB, 0, stream>>>(dst, deg, E);
    cnt_kernel<<<(N + TB - 1) / TB, TB, 0, stream>>>(batch, cnt, N);
    scan1_kernel<<<nScanBlocks, 256, 0, stream>>>(deg, thrPfx, blkSums, N);
    scan2_kernel<<<1, 1024, 0, stream>>>(blkSums, nScanBlocks);
    scan3_kernel<<<nScanBlocks, 256, 0, stream>>>(deg, thrPfx, blkSums, offsets, cursor, N, E);
    fill_kernel<<<(E + TB - 1) / TB, TB, 0, stream>>>(src, dst, cursor, csr_src, E);

    // layer 1: aggregate x (D=32), dense 32->64 + relu -> h1
    agg_kernel<32><<<((size_t)N * 8 + TB - 1) / TB, TB, 0, stream>>>(x, csr_src, offsets, agg, N);
    dense_kernel<32, false><<<(N + 3) / 4, TB, 0, stream>>>(agg, x, W1_l, W1_r, b1, h1,
                                                            nullptr, nullptr, N);

    // layer 2: aggregate h1 (D=64), dense 64->64 + relu fused with pooling
    agg_kernel<64><<<((size_t)N * 16 + TB - 1) / TB, TB, 0, stream>>>(h1, csr_src, offsets, agg, N);
    dense_kernel<64, true><<<(N + 3) / 4, TB, 0, stream>>>(agg, h1, W2_l, W2_r, b2, nullptr,
                                                           batch, pool, N);

    final_kernel<<<(G * 2 + TB - 1) / TB, TB, 0, stream>>>(pool, cnt, W_lin, b_lin, out, G);
}

// Round 3
// 721.717 us; speedup vs baseline: 2.0712x; 1.4531x over previous
//
#include <hip/hip_runtime.h>
#include <hip/hip_bf16.h>

// JetGNN: 2-layer SAGEConv(mean) + ReLU + global_mean_pool + Linear(64->2)
// R1: hierarchical scan (454us single-block scan -> ~30us).
// R2: replaced deg+fill scatter CSR build (fill alone 288us, WRITE_SIZE 203MB
//     from 16x line amplification) with two-level bucketed counting sort:
//     all scatters land in L2-dense runs; packed 4B records.

#define WS_ALIGN 64
#define EPB 4096          // edges per block in bucket_scatter (256 thr x 16)
#define BSHIFT 10         // 1024 nodes per bucket
#define BNODES 1024

// ---------- pooling counts ----------

__global__ void cnt_kernel(const int* __restrict__ batch, int* __restrict__ cnt, int N) {
    int i = blockIdx.x * blockDim.x + threadIdx.x;
    if (i < N) atomicAdd(&cnt[batch[i]], 1);
}

// ---------- bucketed CSR construction ----------
// bucket b = dst >> BSHIFT covers nodes [b*1024, (b+1)*1024). NB <= 256.

__global__ __launch_bounds__(256) void bucket_hist_kernel(const int* __restrict__ dst,
                                                          int* __restrict__ bucketCount, int E) {
    __shared__ int hist[256];
    const int t = threadIdx.x;
    hist[t] = 0;
    __syncthreads();
    for (int e = blockIdx.x * blockDim.x + t; e < E; e += gridDim.x * blockDim.x)
        atomicAdd(&hist[dst[e] >> BSHIFT], 1);
    __syncthreads();
    if (hist[t] > 0) atomicAdd(&bucketCount[t], hist[t]);
}

__global__ __launch_bounds__(256) void bucket_scan_kernel(const int* __restrict__ bucketCount,
                                                          int* __restrict__ bucketBase,
                                                          int* __restrict__ bucketCursor,
                                                          int NB, int E) {
    __shared__ int s[256];
    const int t = threadIdx.x;
    int v = (t < NB) ? bucketCount[t] : 0;
    s[t] = v;
    __syncthreads();
    for (int off = 1; off < 256; off <<= 1) {
        int u = (t >= off) ? s[t - off] : 0;
        __syncthreads();
        s[t] += u;
        __syncthreads();
    }
    int excl = s[t] - v;
    if (t < NB) { bucketBase[t] = excl; bucketCursor[t] = excl; }
    if (t == 0) bucketBase[NB] = E;
}

// each block: LDS hist over its 4096 edges, one global atomic per bucket to
// reserve a contiguous run, then write packed (src<<10|dstLocal) records.
__global__ __launch_bounds__(256) void bucket_scatter_kernel(const int* __restrict__ src,
                                                             const int* __restrict__ dst,
                                                             int* __restrict__ bucketCursor,
                                                             unsigned* __restrict__ bucketData,
                                                             int E, int NB) {
    __shared__ int hist[256];
    __shared__ int cur[256];
    const int t = threadIdx.x;
    hist[t] = 0;
    __syncthreads();
    const int eBase = blockIdx.x * EPB + t;
    int s[16], b[16], dl[16];
#pragma unroll
    for (int j = 0; j < 16; ++j) {
        int e = eBase + j * 256;
        if (e < E) {
            int d = dst[e];
            s[j]  = src[e];
            b[j]  = d >> BSHIFT;
            dl[j] = d & (BNODES - 1);
            atomicAdd(&hist[b[j]], 1);
        } else {
            b[j] = -1;
        }
    }
    __syncthreads();
    if (t < NB && hist[t] > 0) cur[t] = atomicAdd(&bucketCursor[t], hist[t]);
    __syncthreads();
#pragma unroll
    for (int j = 0; j < 16; ++j) {
        if (b[j] >= 0) {
            int pos = atomicAdd(&cur[b[j]], 1);
            bucketData[pos] = ((unsigned)s[j] << BSHIFT) | (unsigned)dl[j];
        }
    }
}

// one block per bucket: count per-node deg in LDS, scan 1024 counts, write
// offsets coalesced, then scatter src into the bucket's contiguous csr range.
__global__ __launch_bounds__(256) void csr_build_kernel(const unsigned* __restrict__ bucketData,
                                                        const int* __restrict__ bucketBase,
                                                        int* __restrict__ offsets,
                                                        int* __restrict__ csr_src,
                                                        int N, int E, int NB) {
    __shared__ int cnt[BNODES];
    __shared__ int sscan[256];
    __shared__ int cur[BNODES];
    const int t   = threadIdx.x;
    const int bkt = blockIdx.x;
    const int beg = bucketBase[bkt];
    const int end = bucketBase[bkt + 1];
    for (int i = t; i < BNODES; i += 256) cnt[i] = 0;
    __syncthreads();
    for (int k = beg + t; k < end; k += 256)
        atomicAdd(&cnt[bucketData[k] & (BNODES - 1)], 1);
    __syncthreads();
    // exclusive scan of cnt[1024]: 4 sequential per thread + block scan
    int local[4];
    int sum = 0;
#pragma unroll
    for (int j = 0; j < 4; ++j) { local[j] = sum; sum += cnt[t * 4 + j]; }
    sscan[t] = sum;
    __syncthreads();
    for (int off = 1; off < 256; off <<= 1) {
        int v = (t >= off) ? sscan[t - off] : 0;
        __syncthreads();
        sscan[t] += v;
        __syncthreads();
    }
    int base = (t > 0) ? sscan[t - 1] : 0;
#pragma unroll
    for (int j = 0; j < 4; ++j) cur[t * 4 + j] = base + local[j];
    __syncthreads();
    for (int i = t; i < BNODES; i += 256) {
        int node = (bkt << BSHIFT) + i;
        if (node <= N) offsets[node] = beg + cur[i];
    }
    if (bkt == NB - 1 && t == 0 && (NB << BSHIFT) == N) offsets[N] = E; // N%1024==0 case
    __syncthreads();
    for (int k = beg + t; k < end; k += 256) {
        unsigned v = bucketData[k];
        int d   = (int)(v & (BNODES - 1));
        int pos = beg + atomicAdd(&cur[d], 1);
        csr_src[pos] = (int)(v >> BSHIFT);
    }
}

// ---------- mean aggregation (node-parallel, D/4 threads per node) ----------

template <int D>
__global__ void agg_kernel(const float* __restrict__ feat,
                           const int* __restrict__ csr_src,
                           const int* __restrict__ offsets,
                           float* __restrict__ agg, int N) {
    constexpr int TPN = D / 4;
    int tid  = blockIdx.x * blockDim.x + threadIdx.x;
    int node = tid / TPN;
    int part = tid % TPN;
    if (node >= N) return;
    const int beg = offsets[node];
    const int end = offsets[node + 1];
    float4 acc = make_float4(0.f, 0.f, 0.f, 0.f);
    for (int k = beg; k < end; ++k) {
        int s = csr_src[k];
        const float4 v = *reinterpret_cast<const float4*>(feat + (size_t)s * D + part * 4);
        acc.x += v.x; acc.y += v.y; acc.z += v.z; acc.w += v.w;
    }
    const float inv = 1.0f / fmaxf((float)(end - beg), 1.0f);
    acc.x *= inv; acc.y *= inv; acc.z *= inv; acc.w *= inv;
    *reinterpret_cast<float4*>(agg + (size_t)node * D + part * 4) = acc;
}

// ---------- dense: out[i][o] = relu(agg[i]·Wl[o] + x[i]·Wr[o] + b[o]) ----------

template <int DIN, bool POOL>
__launch_bounds__(256)
__global__ void dense_kernel(const float* __restrict__ agg,
                             const float* __restrict__ xin,
                             const float* __restrict__ Wl,
                             const float* __restrict__ Wr,
                             const float* __restrict__ bias,
                             float* __restrict__ hout,
                             const int* __restrict__ batch,
                             float* __restrict__ pool_sum,
                             int N) {
    constexpr int PAD = DIN + 1;
    __shared__ float Wl_s[64 * PAD];
    __shared__ float Wr_s[64 * PAD];
    __shared__ float a_s[4 * DIN];
    __shared__ float x_s[4 * DIN];
    const int tid = threadIdx.x;
    for (int i = tid; i < 64 * DIN; i += 256) {
        int r = i / DIN, c = i % DIN;
        Wl_s[r * PAD + c] = Wl[i];
        Wr_s[r * PAD + c] = Wr[i];
    }
    const int ln   = tid >> 6;
    const int o    = tid & 63;
    const int node = blockIdx.x * 4 + ln;
    if (o < DIN && node < N) {
        a_s[ln * DIN + o] = agg[(size_t)node * DIN + o];
        x_s[ln * DIN + o] = xin[(size_t)node * DIN + o];
    }
    __syncthreads();
    if (node >= N) return;
    float acc = bias[o];
#pragma unroll
    for (int c = 0; c < DIN; ++c) {
        acc = fmaf(a_s[ln * DIN + c], Wl_s[o * PAD + c], acc);
        acc = fmaf(x_s[ln * DIN + c], Wr_s[o * PAD + c], acc);
    }
    acc = fmaxf(acc, 0.0f);
    if (POOL) {
        atomicAdd(&pool_sum[(size_t)batch[node] * 64 + o], acc);
    } else {
        hout[(size_t)node * 64 + o] = acc;
    }
}

// ---------- head ----------

__global__ void final_kernel(const float* __restrict__ pool_sum,
                             const int* __restrict__ cnt,
                             const float* __restrict__ W_lin,
                             const float* __restrict__ b_lin,
                             float* __restrict__ out, int G) {
    int t = blockIdx.x * blockDim.x + threadIdx.x;
    if (t >= G * 2) return;
    int g = t >> 1, o = t & 1;
    float inv = 1.0f / fmaxf((float)cnt[g], 1.0f);
    float acc = b_lin[o];
#pragma unroll
    for (int c = 0; c < 64; ++c)
        acc = fmaf(pool_sum[(size_t)g * 64 + c] * inv, W_lin[o * 64 + c], acc);
    out[t] = acc;
}

extern "C" void kernel_launch(void* const* d_in, const int* in_sizes, int n_in,
                              void* d_out, int out_size, void* d_ws, size_t ws_size,
                              hipStream_t stream) {
    const float* x     = (const float*)d_in[0];
    const int*   ei    = (const int*)d_in[1];
    const int*   batch = (const int*)d_in[2];
    const float* W1_l  = (const float*)d_in[3];
    const float* b1    = (const float*)d_in[4];
    const float* W1_r  = (const float*)d_in[5];
    const float* W2_l  = (const float*)d_in[6];
    const float* b2    = (const float*)d_in[7];
    const float* W2_r  = (const float*)d_in[8];
    const float* W_lin = (const float*)d_in[9];
    const float* b_lin = (const float*)d_in[10];

    const int N = in_sizes[0] / 32;
    const int E = in_sizes[1] / 2;
    const int G = out_size / 2;
    const int* src = ei;
    const int* dst = ei + E;
    const int NB = (N + BNODES - 1) >> BSHIFT;   // 196 for N=200000 (must be <=256)

    char* p = (char*)d_ws;
    auto carve = [&](size_t bytes) -> void* {
        void* r = (void*)p;
        p += (bytes + (WS_ALIGN - 1)) / WS_ALIGN * WS_ALIGN;
        return r;
    };
    int*      bucketCount  = (int*)carve(256 * 4);
    int*      bucketBase   = (int*)carve(257 * 4);
    int*      bucketCursor = (int*)carve(256 * 4);
    unsigned* bucketData   = (unsigned*)carve((size_t)E * 4);
    int*      offsets      = (int*)carve((size_t)(N + 1) * 4);
    int*      csr_src      = (int*)carve((size_t)E * 4);
    float*    agg          = (float*)carve((size_t)N * 64 * 4);
    float*    h1           = (float*)carve((size_t)N * 64 * 4);
    float*    pool         = (float*)carve((size_t)G * 64 * 4);
    int*      cnt          = (int*)carve((size_t)G * 4);
    float*    out          = (float*)d_out;

    hipMemsetAsync(bucketCount, 0, 256 * 4, stream);
    hipMemsetAsync(pool, 0, (size_t)G * 64 * 4, stream);
    hipMemsetAsync(cnt, 0, (size_t)G * 4, stream);

    const int TB = 256;
    cnt_kernel<<<(N + TB - 1) / TB, TB, 0, stream>>>(batch, cnt, N);
    bucket_hist_kernel<<<1024, TB, 0, stream>>>(dst, bucketCount, E);
    bucket_scan_kernel<<<1, TB, 0, stream>>>(bucketCount, bucketBase, bucketCursor, NB, E);
    bucket_scatter_kernel<<<(E + EPB - 1) / EPB, TB, 0, stream>>>(src, dst, bucketCursor,
                                                                  bucketData, E, NB);
    csr_build_kernel<<<NB, TB, 0, stream>>>(bucketData, bucketBase, offsets, csr_src, N, E, NB);

    // layer 1: aggregate x (D=32), dense 32->64 + relu -> h1
    agg_kernel<32><<<((size_t)N * 8 + TB - 1) / TB, TB, 0, stream>>>(x, csr_src, offsets, agg, N);
    dense_kernel<32, false><<<(N + 3) / 4, TB, 0, stream>>>(agg, x, W1_l, W1_r, b1, h1,
                                                            nullptr, nullptr, N);

    // layer 2: aggregate h1 (D=64), dense 64->64 + relu fused with pooling
    agg_kernel<64><<<((size_t)N * 16 + TB - 1) / TB, TB, 0, stream>>>(h1, csr_src, offsets, agg, N);
    dense_kernel<64, true><<<(N + 3) / 4, TB, 0, stream>>>(agg, h1, W2_l, W2_r, b2, nullptr,
                                                           batch, pool, N);

    final_kernel<<<(G * 2 + TB - 1) / TB, TB, 0, stream>>>(pool, cnt, W_lin, b_lin, out, G);
}

// Round 4
// 707.407 us; speedup vs baseline: 2.1130x; 1.0202x over previous
//
#include <hip/hip_runtime.h>
#include <hip/hip_bf16.h>

// JetGNN: 2-layer SAGEConv(mean) + ReLU + global_mean_pool + Linear(64->2)
// R1: hierarchical scan. R2: bucketed counting-sort CSR build.
// R3: dense rewrite — weights-in-VGPR (lane=out channel, wave=node strip),
//     no LDS, uniform feature loads; pooling uses sorted-batch run detection
//     (one atomic flush per graph run instead of per node: 50MB->~6MB HBM
//     atomic traffic). Old version was LDS-issue-bound (2 ds_read per FMA).

#define WS_ALIGN 64
#define EPB 4096          // edges per block in bucket_scatter (256 thr x 16)
#define BSHIFT 10         // 1024 nodes per bucket
#define BNODES 1024

// ---------- pooling counts ----------

__global__ void cnt_kernel(const int* __restrict__ batch, int* __restrict__ cnt, int N) {
    int i = blockIdx.x * blockDim.x + threadIdx.x;
    if (i < N) atomicAdd(&cnt[batch[i]], 1);
}

// ---------- bucketed CSR construction ----------

__global__ __launch_bounds__(256) void bucket_hist_kernel(const int* __restrict__ dst,
                                                          int* __restrict__ bucketCount, int E) {
    __shared__ int hist[256];
    const int t = threadIdx.x;
    hist[t] = 0;
    __syncthreads();
    for (int e = blockIdx.x * blockDim.x + t; e < E; e += gridDim.x * blockDim.x)
        atomicAdd(&hist[dst[e] >> BSHIFT], 1);
    __syncthreads();
    if (hist[t] > 0) atomicAdd(&bucketCount[t], hist[t]);
}

__global__ __launch_bounds__(256) void bucket_scan_kernel(const int* __restrict__ bucketCount,
                                                          int* __restrict__ bucketBase,
                                                          int* __restrict__ bucketCursor,
                                                          int NB, int E) {
    __shared__ int s[256];
    const int t = threadIdx.x;
    int v = (t < NB) ? bucketCount[t] : 0;
    s[t] = v;
    __syncthreads();
    for (int off = 1; off < 256; off <<= 1) {
        int u = (t >= off) ? s[t - off] : 0;
        __syncthreads();
        s[t] += u;
        __syncthreads();
    }
    int excl = s[t] - v;
    if (t < NB) { bucketBase[t] = excl; bucketCursor[t] = excl; }
    if (t == 0) bucketBase[NB] = E;
}

__global__ __launch_bounds__(256) void bucket_scatter_kernel(const int* __restrict__ src,
                                                             const int* __restrict__ dst,
                                                             int* __restrict__ bucketCursor,
                                                             unsigned* __restrict__ bucketData,
                                                             int E, int NB) {
    __shared__ int hist[256];
    __shared__ int cur[256];
    const int t = threadIdx.x;
    hist[t] = 0;
    __syncthreads();
    const int eBase = blockIdx.x * EPB + t;
    int s[16], b[16], dl[16];
#pragma unroll
    for (int j = 0; j < 16; ++j) {
        int e = eBase + j * 256;
        if (e < E) {
            int d = dst[e];
            s[j]  = src[e];
            b[j]  = d >> BSHIFT;
            dl[j] = d & (BNODES - 1);
            atomicAdd(&hist[b[j]], 1);
        } else {
            b[j] = -1;
        }
    }
    __syncthreads();
    if (t < NB && hist[t] > 0) cur[t] = atomicAdd(&bucketCursor[t], hist[t]);
    __syncthreads();
#pragma unroll
    for (int j = 0; j < 16; ++j) {
        if (b[j] >= 0) {
            int pos = atomicAdd(&cur[b[j]], 1);
            bucketData[pos] = ((unsigned)s[j] << BSHIFT) | (unsigned)dl[j];
        }
    }
}

__global__ __launch_bounds__(256) void csr_build_kernel(const unsigned* __restrict__ bucketData,
                                                        const int* __restrict__ bucketBase,
                                                        int* __restrict__ offsets,
                                                        int* __restrict__ csr_src,
                                                        int N, int E, int NB) {
    __shared__ int cnt[BNODES];
    __shared__ int sscan[256];
    __shared__ int cur[BNODES];
    const int t   = threadIdx.x;
    const int bkt = blockIdx.x;
    const int beg = bucketBase[bkt];
    const int end = bucketBase[bkt + 1];
    for (int i = t; i < BNODES; i += 256) cnt[i] = 0;
    __syncthreads();
    for (int k = beg + t; k < end; k += 256)
        atomicAdd(&cnt[bucketData[k] & (BNODES - 1)], 1);
    __syncthreads();
    int local[4];
    int sum = 0;
#pragma unroll
    for (int j = 0; j < 4; ++j) { local[j] = sum; sum += cnt[t * 4 + j]; }
    sscan[t] = sum;
    __syncthreads();
    for (int off = 1; off < 256; off <<= 1) {
        int v = (t >= off) ? sscan[t - off] : 0;
        __syncthreads();
        sscan[t] += v;
        __syncthreads();
    }
    int base = (t > 0) ? sscan[t - 1] : 0;
#pragma unroll
    for (int j = 0; j < 4; ++j) cur[t * 4 + j] = base + local[j];
    __syncthreads();
    for (int i = t; i < BNODES; i += 256) {
        int node = (bkt << BSHIFT) + i;
        if (node <= N) offsets[node] = beg + cur[i];
    }
    if (bkt == NB - 1 && t == 0 && (NB << BSHIFT) == N) offsets[N] = E;
    __syncthreads();
    for (int k = beg + t; k < end; k += 256) {
        unsigned v = bucketData[k];
        int d   = (int)(v & (BNODES - 1));
        int pos = beg + atomicAdd(&cur[d], 1);
        csr_src[pos] = (int)(v >> BSHIFT);
    }
}

// ---------- mean aggregation (node-parallel, D/4 threads per node) ----------

template <int D>
__global__ void agg_kernel(const float* __restrict__ feat,
                           const int* __restrict__ csr_src,
                           const int* __restrict__ offsets,
                           float* __restrict__ agg, int N) {
    constexpr int TPN = D / 4;
    int tid  = blockIdx.x * blockDim.x + threadIdx.x;
    int node = tid / TPN;
    int part = tid % TPN;
    if (node >= N) return;
    const int beg = offsets[node];
    const int end = offsets[node + 1];
    float4 acc = make_float4(0.f, 0.f, 0.f, 0.f);
    for (int k = beg; k < end; ++k) {
        int s = csr_src[k];
        const float4 v = *reinterpret_cast<const float4*>(feat + (size_t)s * D + part * 4);
        acc.x += v.x; acc.y += v.y; acc.z += v.z; acc.w += v.w;
    }
    const float inv = 1.0f / fmaxf((float)(end - beg), 1.0f);
    acc.x *= inv; acc.y *= inv; acc.z *= inv; acc.w *= inv;
    *reinterpret_cast<float4*>(agg + (size_t)node * D + part * 4) = acc;
}

// ---------- dense: lane = output channel, wave = contiguous 16-node strip ----------
// weights held in VGPRs (lane o owns Wl[o][*], Wr[o][*]); feature rows are
// wave-uniform loads; POOL uses sorted-batch run detection in registers.

template <int DIN, bool POOL>
__launch_bounds__(256)
__global__ void dense_kernel(const float* __restrict__ agg,
                             const float* __restrict__ xin,
                             const float* __restrict__ Wl,
                             const float* __restrict__ Wr,
                             const float* __restrict__ bias,
                             float* __restrict__ hout,
                             const int* __restrict__ batch,
                             float* __restrict__ pool_sum,
                             int N) {
    const int lane = threadIdx.x & 63;
    const int wave = __builtin_amdgcn_readfirstlane((int)(threadIdx.x >> 6));
    float wl[DIN], wr[DIN];
#pragma unroll
    for (int c4 = 0; c4 < DIN / 4; ++c4) {
        const float4 v = *reinterpret_cast<const float4*>(Wl + (size_t)lane * DIN + c4 * 4);
        wl[c4 * 4 + 0] = v.x; wl[c4 * 4 + 1] = v.y; wl[c4 * 4 + 2] = v.z; wl[c4 * 4 + 3] = v.w;
        const float4 u = *reinterpret_cast<const float4*>(Wr + (size_t)lane * DIN + c4 * 4);
        wr[c4 * 4 + 0] = u.x; wr[c4 * 4 + 1] = u.y; wr[c4 * 4 + 2] = u.z; wr[c4 * 4 + 3] = u.w;
    }
    const float b = bias[lane];
    const int nodeBeg = blockIdx.x * 64 + wave * 16;
    float accg = 0.0f;
    int gcur = -1;
    for (int i = 0; i < 16; ++i) {
        const int node = nodeBeg + i;
        if (node >= N) break;                          // wave-uniform
        const float* arow = agg + (size_t)node * DIN;
        const float* xrow = xin + (size_t)node * DIN;
        float acc = b;
#pragma unroll
        for (int c4 = 0; c4 < DIN / 4; ++c4) {
            const float4 av = *reinterpret_cast<const float4*>(arow + c4 * 4);
            const float4 xv = *reinterpret_cast<const float4*>(xrow + c4 * 4);
            acc = fmaf(av.x, wl[c4 * 4 + 0], acc);
            acc = fmaf(av.y, wl[c4 * 4 + 1], acc);
            acc = fmaf(av.z, wl[c4 * 4 + 2], acc);
            acc = fmaf(av.w, wl[c4 * 4 + 3], acc);
            acc = fmaf(xv.x, wr[c4 * 4 + 0], acc);
            acc = fmaf(xv.y, wr[c4 * 4 + 1], acc);
            acc = fmaf(xv.z, wr[c4 * 4 + 2], acc);
            acc = fmaf(xv.w, wr[c4 * 4 + 3], acc);
        }
        acc = fmaxf(acc, 0.0f);
        if (POOL) {
            const int g = batch[node];                 // wave-uniform, sorted
            if (g != gcur) {                           // wave-uniform branch
                if (gcur >= 0) atomicAdd(&pool_sum[(size_t)gcur * 64 + lane], accg);
                gcur = g;
                accg = 0.0f;
            }
            accg += acc;
        } else {
            hout[(size_t)node * 64 + lane] = acc;      // coalesced 256B/wave
        }
    }
    if (POOL && gcur >= 0) atomicAdd(&pool_sum[(size_t)gcur * 64 + lane], accg);
}

// ---------- head ----------

__global__ void final_kernel(const float* __restrict__ pool_sum,
                             const int* __restrict__ cnt,
                             const float* __restrict__ W_lin,
                             const float* __restrict__ b_lin,
                             float* __restrict__ out, int G) {
    int t = blockIdx.x * blockDim.x + threadIdx.x;
    if (t >= G * 2) return;
    int g = t >> 1, o = t & 1;
    float inv = 1.0f / fmaxf((float)cnt[g], 1.0f);
    float acc = b_lin[o];
#pragma unroll
    for (int c = 0; c < 64; ++c)
        acc = fmaf(pool_sum[(size_t)g * 64 + c] * inv, W_lin[o * 64 + c], acc);
    out[t] = acc;
}

extern "C" void kernel_launch(void* const* d_in, const int* in_sizes, int n_in,
                              void* d_out, int out_size, void* d_ws, size_t ws_size,
                              hipStream_t stream) {
    const float* x     = (const float*)d_in[0];
    const int*   ei    = (const int*)d_in[1];
    const int*   batch = (const int*)d_in[2];
    const float* W1_l  = (const float*)d_in[3];
    const float* b1    = (const float*)d_in[4];
    const float* W1_r  = (const float*)d_in[5];
    const float* W2_l  = (const float*)d_in[6];
    const float* b2    = (const float*)d_in[7];
    const float* W2_r  = (const float*)d_in[8];
    const float* W_lin = (const float*)d_in[9];
    const float* b_lin = (const float*)d_in[10];

    const int N = in_sizes[0] / 32;
    const int E = in_sizes[1] / 2;
    const int G = out_size / 2;
    const int* src = ei;
    const int* dst = ei + E;
    const int NB = (N + BNODES - 1) >> BSHIFT;   // 196 for N=200000

    char* p = (char*)d_ws;
    auto carve = [&](size_t bytes) -> void* {
        void* r = (void*)p;
        p += (bytes + (WS_ALIGN - 1)) / WS_ALIGN * WS_ALIGN;
        return r;
    };
    int*      bucketCount  = (int*)carve(256 * 4);
    int*      bucketBase   = (int*)carve(257 * 4);
    int*      bucketCursor = (int*)carve(256 * 4);
    unsigned* bucketData   = (unsigned*)carve((size_t)E * 4);
    int*      offsets      = (int*)carve((size_t)(N + 1) * 4);
    int*      csr_src      = (int*)carve((size_t)E * 4);
    float*    agg          = (float*)carve((size_t)N * 64 * 4);
    float*    h1           = (float*)carve((size_t)N * 64 * 4);
    float*    pool         = (float*)carve((size_t)G * 64 * 4);
    int*      cnt          = (int*)carve((size_t)G * 4);
    float*    out          = (float*)d_out;

    hipMemsetAsync(bucketCount, 0, 256 * 4, stream);
    hipMemsetAsync(pool, 0, (size_t)G * 64 * 4, stream);
    hipMemsetAsync(cnt, 0, (size_t)G * 4, stream);

    const int TB = 256;
    cnt_kernel<<<(N + TB - 1) / TB, TB, 0, stream>>>(batch, cnt, N);
    bucket_hist_kernel<<<1024, TB, 0, stream>>>(dst, bucketCount, E);
    bucket_scan_kernel<<<1, TB, 0, stream>>>(bucketCount, bucketBase, bucketCursor, NB, E);
    bucket_scatter_kernel<<<(E + EPB - 1) / EPB, TB, 0, stream>>>(src, dst, bucketCursor,
                                                                  bucketData, E, NB);
    csr_build_kernel<<<NB, TB, 0, stream>>>(bucketData, bucketBase, offsets, csr_src, N, E, NB);

    // layer 1: aggregate x (D=32), dense 32->64 + relu -> h1
    agg_kernel<32><<<((size_t)N * 8 + TB - 1) / TB, TB, 0, stream>>>(x, csr_src, offsets, agg, N);
    dense_kernel<32, false><<<(N + 63) / 64, TB, 0, stream>>>(agg, x, W1_l, W1_r, b1, h1,
                                                              nullptr, nullptr, N);

    // layer 2: aggregate h1 (D=64), dense 64->64 + relu fused with pooling
    agg_kernel<64><<<((size_t)N * 16 + TB - 1) / TB, TB, 0, stream>>>(h1, csr_src, offsets, agg, N);
    dense_kernel<64, true><<<(N + 63) / 64, TB, 0, stream>>>(agg, h1, W2_l, W2_r, b2, nullptr,
                                                             batch, pool, N);

    final_kernel<<<(G * 2 + TB - 1) / TB, TB, 0, stream>>>(pool, cnt, W_lin, b_lin, out, G);
}